// Round 10
// baseline (268.381 us; speedup 1.0000x reference)
//
#include <hip/hip_runtime.h>
#include <cstddef>

#define SS 1024
#define DF 768
#define NBATCH 16
#define GAT_ALPHA 0.2f

typedef _Float16 f16x8 __attribute__((ext_vector_type(8)));
typedef _Float16 f16x4 __attribute__((ext_vector_type(4)));
typedef float f32x4 __attribute__((ext_vector_type(4)));

// async global->LDS, 16B per lane. LDS dest is wave-uniform base + lane*16.
__device__ __forceinline__ void gload16(const void* g, void* l) {
  __builtin_amdgcn_global_load_lds(
      (const __attribute__((address_space(1))) void*)g,
      (__attribute__((address_space(3))) void*)l, 16, 0, 0);
}

__device__ __forceinline__ float lrelu(float t) {
  return fmaxf(t, GAT_ALPHA * t);
}

// ---------------------------------------------------------------------------
// fp32 -> fp16 convert, 4 elems/thread
// ---------------------------------------------------------------------------
__global__ __launch_bounds__(256) void f32tof16_k(const float* __restrict__ in,
                                                  _Float16* __restrict__ out,
                                                  int n) {
  int idx = (blockIdx.x * 256 + threadIdx.x) * 4;
  if (idx + 3 < n) {
    float4 v = *(const float4*)&in[idx];
    f16x4 o;
    o[0] = (_Float16)v.x;
    o[1] = (_Float16)v.y;
    o[2] = (_Float16)v.z;
    o[3] = (_Float16)v.w;
    *(f16x4*)&out[idx] = o;
  }
}

// ---------------------------------------------------------------------------
// pack: int32 mask (64MB) -> bitmask (2MB). byte t holds j=8t..8t+7 (bit k).
// ---------------------------------------------------------------------------
__global__ __launch_bounds__(256) void pack_k(const int* __restrict__ mask,
                                              unsigned char* __restrict__ bm) {
  const size_t t = (size_t)blockIdx.x * 256 + threadIdx.x;  // byte idx, 2M
  const int* mp = mask + t * 8;
  const int4 a = *(const int4*)mp;
  const int4 c = *(const int4*)(mp + 4);
  unsigned v = (unsigned)(a.x > 0) | ((unsigned)(a.y > 0) << 1) |
               ((unsigned)(a.z > 0) << 2) | ((unsigned)(a.w > 0) << 3) |
               ((unsigned)(c.x > 0) << 4) | ((unsigned)(c.y > 0) << 5) |
               ((unsigned)(c.z > 0) << 6) | ((unsigned)(c.w > 0) << 7);
  bm[t] = (unsigned char)v;
}

// ===========================================================================
// m97-style GEMM core: 256 threads, 4 waves (2x2), BM=BN=128, BK=32, 2-slot
// 32KB LDS dbuf, window = {__syncthreads; stage(t+1); 8 ds_read; 16 MFMA}.
// XOR chunk swizzle both-sides (conflict-free ds_read_b128); XCD swizzle.
// Occupancy target: 3 blocks/CU (12 waves/CU) via launch_bounds(256,3).
// Safety: wave's ds_reads(t-1) retire before its MFMA(t-1) (lgkmcnt), and
// sync at window top (lgkm0+vmcnt0+barrier) fences all waves before slot
// t+1 (== t-1) is overwritten by stage.
// ===========================================================================

// ---------------------------------------------------------------------------
// GEMM1: hT16[b][n][s] = f16( sum_k X16[m,k]*W16[n,k] + Wb[n] ), m=b*1024+s
// Epilogue: per-wave LDS transpose (64x64, pad 72) -> coalesced hT write +
// fused rowdots partials psi6/psj6[nt][m] (nt = n-tile 0..5).
// ---------------------------------------------------------------------------
__global__ __launch_bounds__(256, 3) void gemm1_k(
    const _Float16* __restrict__ X16, const _Float16* __restrict__ W16,
    const float* __restrict__ Wbl, const float* __restrict__ Al,
    _Float16* __restrict__ hT16, float* __restrict__ psi6,
    float* __restrict__ psj6) {
  // loop: 2 slots x 16KB = 32KB; epilogue: tb 4x9216 + av 1KB + pw 2KB
  __shared__ __align__(16) char smem[39936];
  const int flat = blockIdx.x + 128 * blockIdx.y;  // grid (128,6) = 768
  const int swz = (flat & 7) * 96 + (flat >> 3);   // XCD-chunked (768%8==0)
  const int m0 = (swz & 127) * 128;
  const int nt = swz >> 7;  // 0..5
  const int n0 = nt * 128;
  const int tid = threadIdx.x;
  const int w = tid >> 6, lane = tid & 63;
  const int wr = w >> 1, wc = w & 1;

  const int sk8 = ((tid & 3) ^ ((tid >> 3) & 3)) * 8;      // swizzled src
  const int rby = ((lane >> 4) ^ ((lane >> 1) & 3)) * 16;  // swizzled read
  const int rrow = lane & 15;

  f32x4 acc[4][4];
#pragma unroll
  for (int mi = 0; mi < 4; ++mi)
#pragma unroll
    for (int ni = 0; ni < 4; ++ni) acc[mi][ni] = (f32x4)(0.f);

#define STG1(s, kt)                                                     \
  {                                                                     \
    _Pragma("unroll") for (int q = 0; q < 2; ++q) {                     \
      const int row = q * 64 + (tid >> 2);                              \
      gload16(&X16[(size_t)(m0 + row) * DF + (kt) * 32 + sk8],          \
              smem + (s) * 16384 + q * 4096 + w * 1024);                \
      gload16(&W16[(size_t)(n0 + row) * DF + (kt) * 32 + sk8],          \
              smem + (s) * 16384 + 8192 + q * 4096 + w * 1024);         \
    }                                                                   \
  }

  const int NT = DF / 32;  // 24
  STG1(0, 0);
  for (int t = 0; t < NT; ++t) {
    __syncthreads();  // vmcnt0: slot t ready; lgkm0: slot t+1 readers done
    if (t + 1 < NT) STG1((t + 1) & 1, t + 1);
    const char* Ab = smem + (t & 1) * 16384;
    const char* Bb = Ab + 8192;
    f16x8 afr[4], bfr[4];
#pragma unroll
    for (int mi = 0; mi < 4; ++mi)
      afr[mi] = *(const f16x8*)(Ab + (wr * 64 + mi * 16 + rrow) * 64 + rby);
#pragma unroll
    for (int ni = 0; ni < 4; ++ni)
      bfr[ni] = *(const f16x8*)(Bb + (wc * 64 + ni * 16 + rrow) * 64 + rby);
#pragma unroll
    for (int mi = 0; mi < 4; ++mi)
#pragma unroll
      for (int ni = 0; ni < 4; ++ni)
        acc[mi][ni] = __builtin_amdgcn_mfma_f32_16x16x32_f16(
            afr[mi], bfr[ni], acc[mi][ni], 0, 0, 0);
  }
#undef STG1

  // ---- epilogue: transpose + fused rowdots + coalesced hT write ----
  __syncthreads();
  float* asrc = (float*)(smem + 36864);  // 128 f32
  float* adst = asrc + 128;
  float* pwsi = (float*)(smem + 37888);  // [128][2]
  float* pwsj = pwsi + 256;
  if (tid < 128) {
    asrc[tid] = Al[n0 + tid];
    adst[tid] = Al[DF + n0 + tid];
  }
  _Float16* tb = (_Float16*)smem + w * 4608;  // 64 cols x 72 (pad)
  const int cg = lane >> 4, cr = lane & 15;
  float bias[4];
#pragma unroll
  for (int ni = 0; ni < 4; ++ni) bias[ni] = Wbl[n0 + wc * 64 + ni * 16 + cr];
#pragma unroll
  for (int mi = 0; mi < 4; ++mi) {
#pragma unroll
    for (int ni = 0; ni < 4; ++ni) {
      f16x4 tv;
#pragma unroll
      for (int r = 0; r < 4; ++r)
        tv[r] = (_Float16)(acc[mi][ni][r] + bias[ni]);
      *(f16x4*)&tb[(ni * 16 + cr) * 72 + mi * 16 + cg * 4] = tv;
    }
  }
  __syncthreads();
  // rowdots: lane = wave-local row (0..63); sum over wave's 64 cols
  {
    float ps = 0.f, pd = 0.f;
    const float* wa = asrc + wc * 64;
    const float* wd = adst + wc * 64;
#pragma unroll 8
    for (int c = 0; c < 64; ++c) {
      const float hv = (float)tb[c * 72 + lane];
      ps = fmaf(hv, wa[c], ps);
      pd = fmaf(hv, wd[c], pd);
    }
    pwsi[(wr * 64 + lane) * 2 + wc] = ps;
    pwsj[(wr * 64 + lane) * 2 + wc] = pd;
  }
  // coalesced hT write: 128B contiguous per col
  const int bb = m0 >> 10;
  const int s0w = (m0 & 1023) + wr * 64;
#pragma unroll
  for (int pass = 0; pass < 8; ++pass) {
    const int cl = pass * 8 + (lane >> 3);
    f16x8 v = *(const f16x8*)&tb[cl * 72 + (lane & 7) * 8];
    *(f16x8*)&hT16[((size_t)bb * DF + n0 + wc * 64 + cl) * SS + s0w +
                   (lane & 7) * 8] = v;
  }
  __syncthreads();
  if (tid < 128) {
    psi6[nt * 16384 + m0 + tid] = pwsi[tid * 2] + pwsi[tid * 2 + 1];
    psj6[nt * 16384 + m0 + tid] = pwsj[tid * 2] + pwsj[tid * 2 + 1];
  }
}

// ---------------------------------------------------------------------------
// GEMM2: out[b,i,d] = sum_j P16[b,i,j] * hT16[b,d,j]   (K=1024)
// ---------------------------------------------------------------------------
__global__ __launch_bounds__(256, 3) void gemm2_k(
    const _Float16* __restrict__ P16, const _Float16* __restrict__ hT16,
    float* __restrict__ outl, _Float16* __restrict__ X16n, int writeX) {
  __shared__ __align__(16) char smem[32768];  // 2 slots x 16KB
  const int flat = blockIdx.x + 8 * (blockIdx.y + 6 * blockIdx.z);  // 768
  const int swz = (flat & 7) * 96 + (flat >> 3);  // XCD gets 2 batches
  const int i0 = (swz & 7) * 128;
  const int d0 = ((swz >> 3) % 6) * 128;
  const int b = swz / 48;
  const int tid = threadIdx.x;
  const int w = tid >> 6, lane = tid & 63;
  const int wr = w >> 1, wc = w & 1;

  const int sk8 = ((tid & 3) ^ ((tid >> 3) & 3)) * 8;
  const int rby = ((lane >> 4) ^ ((lane >> 1) & 3)) * 16;
  const int rrow = lane & 15;

  const _Float16* Pb = P16 + ((size_t)b << 20);
  const _Float16* hTb = hT16 + (size_t)b * DF * SS;

  f32x4 acc[4][4];
#pragma unroll
  for (int mi = 0; mi < 4; ++mi)
#pragma unroll
    for (int ni = 0; ni < 4; ++ni) acc[mi][ni] = (f32x4)(0.f);

#define STG2(s, kt)                                                     \
  {                                                                     \
    _Pragma("unroll") for (int q = 0; q < 2; ++q) {                     \
      const int row = q * 64 + (tid >> 2);                              \
      gload16(&Pb[((size_t)(i0 + row) << 10) + (kt) * 32 + sk8],        \
              smem + (s) * 16384 + q * 4096 + w * 1024);                \
      gload16(&hTb[(size_t)(d0 + row) * SS + (kt) * 32 + sk8],          \
              smem + (s) * 16384 + 8192 + q * 4096 + w * 1024);         \
    }                                                                   \
  }

  const int NT = SS / 32;  // 32
  STG2(0, 0);
  for (int t = 0; t < NT; ++t) {
    __syncthreads();
    if (t + 1 < NT) STG2((t + 1) & 1, t + 1);
    const char* Ab = smem + (t & 1) * 16384;
    const char* Bb = Ab + 8192;
    f16x8 afr[4], bfr[4];
#pragma unroll
    for (int mi = 0; mi < 4; ++mi)
      afr[mi] = *(const f16x8*)(Ab + (wr * 64 + mi * 16 + rrow) * 64 + rby);
#pragma unroll
    for (int ni = 0; ni < 4; ++ni)
      bfr[ni] = *(const f16x8*)(Bb + (wc * 64 + ni * 16 + rrow) * 64 + rby);
#pragma unroll
    for (int mi = 0; mi < 4; ++mi)
#pragma unroll
      for (int ni = 0; ni < 4; ++ni)
        acc[mi][ni] = __builtin_amdgcn_mfma_f32_16x16x32_f16(
            afr[mi], bfr[ni], acc[mi][ni], 0, 0, 0);
  }
#undef STG2

  const int cg = lane >> 4, cr = lane & 15;
#pragma unroll
  for (int mi = 0; mi < 4; ++mi) {
#pragma unroll
    for (int ni = 0; ni < 4; ++ni) {
      const int d = d0 + wc * 64 + ni * 16 + cr;
      const int row0 = i0 + wr * 64 + mi * 16 + cg * 4;
#pragma unroll
      for (int r = 0; r < 4; ++r) {
        float v = acc[mi][ni][r];
        size_t o = ((size_t)b * SS + row0 + r) * DF + d;
        outl[o] = v;
        if (writeX) X16n[o] = (_Float16)v;
      }
    }
  }
}

// ---------------------------------------------------------------------------
// rowfin: combine 6 n-tile partials -> si; per-batch max(si); sjc/refj.
// ---------------------------------------------------------------------------
__global__ __launch_bounds__(256) void rowfin_k(const float* __restrict__ psi6,
                                                const float* __restrict__ psj6,
                                                const float* __restrict__ Abp,
                                                float* __restrict__ si,
                                                float* __restrict__ sjc,
                                                float* __restrict__ refj) {
  const int b = blockIdx.x;
  const int t = threadIdx.x;
  __shared__ float red[256];
  float siv[4], sjv[4];
  float mloc = -1e30f;
#pragma unroll
  for (int q = 0; q < 4; ++q) {
    const int idx = (b << 10) + t + (q << 8);
    float a = 0.f, d = 0.f;
#pragma unroll
    for (int c = 0; c < 6; ++c) {
      a += psi6[c * 16384 + idx];
      d += psj6[c * 16384 + idx];
    }
    siv[q] = a;
    sjv[q] = d;
    si[idx] = a;
    mloc = fmaxf(mloc, a);
  }
  red[t] = mloc;
  __syncthreads();
  for (int off = 128; off > 0; off >>= 1) {
    if (t < off) red[t] = fmaxf(red[t], red[t + off]);
    __syncthreads();
  }
  const float maxsi = red[0];
  const float ab = Abp[0];
#pragma unroll
  for (int q = 0; q < 4; ++q) {
    const int idx = (b << 10) + t + (q << 8);
    const float c = sjv[q] + ab;
    sjc[idx] = c;
    refj[idx] = lrelu(maxsi + c);
  }
}

// ---------------------------------------------------------------------------
// colsum: column partial sums of exp(lrelu(si+sjc)-refj) over masked i.
// ---------------------------------------------------------------------------
__global__ __launch_bounds__(256) void colsum_k(
    const unsigned char* __restrict__ bm, const float* __restrict__ si,
    const float* __restrict__ sjc, const float* __restrict__ refj,
    float* __restrict__ pden) {
  const int g = blockIdx.x;  // 0..31
  const int b = blockIdx.y;  // 0..15
  const int t = threadIdx.x;
  const int jb = t & 127;
  const int half = t >> 7;
  const int row0 = (g << 5) + (half << 4);
  __shared__ float s_si[32];
  if (t < 32) s_si[t] = si[(b << 10) + (g << 5) + t];
  __syncthreads();
  float sc[8], rf[8];
  *(float4*)&sc[0] = *(const float4*)&sjc[(b << 10) + jb * 8];
  *(float4*)&sc[4] = *(const float4*)&sjc[(b << 10) + jb * 8 + 4];
  *(float4*)&rf[0] = *(const float4*)&refj[(b << 10) + jb * 8];
  *(float4*)&rf[4] = *(const float4*)&refj[(b << 10) + jb * 8 + 4];
  float den[8] = {0.f, 0.f, 0.f, 0.f, 0.f, 0.f, 0.f, 0.f};
  const unsigned char* bp = bm + ((size_t)b << 17) + ((size_t)row0 << 7) + jb;
#pragma unroll 4
  for (int r = 0; r < 16; ++r) {
    const unsigned m = bp[(size_t)r << 7];
    const float siv = s_si[(half << 4) + r];
#pragma unroll
    for (int k = 0; k < 8; ++k) {
      if ((m >> k) & 1) den[k] += __expf(lrelu(siv + sc[k]) - rf[k]);
    }
  }
  const size_t o = ((size_t)(g * 2 + half)) * 16384 + (b << 10) + jb * 8;
  *(float4*)&pden[o] = *(float4*)&den[0];
  *(float4*)&pden[o + 4] = *(float4*)&den[4];
}

// combine 64 chunks -> rden (sentinel -1 for fully-masked column)
__global__ __launch_bounds__(256) void colcomb_k(const float* __restrict__ pden,
                                                 float* __restrict__ rden) {
  const int idx = blockIdx.x * 256 + threadIdx.x;  // b*1024 + j
  float s = 0.f;
#pragma unroll
  for (int c = 0; c < 64; ++c) s += pden[(size_t)c * 16384 + idx];
  rden[idx] = (s > 0.f) ? 1.f / s : -1.f;
}

// ---------------------------------------------------------------------------
// punorm2: P16[b][i][j] = normalized attention weight (f16), single bitmask
// pass. rden<0 sentinel => uniform column 1/S (reference's all-masked case).
// ---------------------------------------------------------------------------
__global__ __launch_bounds__(256) void punorm2_k(
    const unsigned char* __restrict__ bm, const float* __restrict__ si,
    const float* __restrict__ sjc, const float* __restrict__ refj,
    const float* __restrict__ rden, _Float16* __restrict__ P16) {
  const int g = blockIdx.x;  // 0..31
  const int b = blockIdx.y;  // 0..15
  const int t = threadIdx.x;
  const int jb = t & 127;
  const int half = t >> 7;
  const int row0 = (g << 5) + (half << 4);
  __shared__ float s_si[32];
  if (t < 32) s_si[t] = si[(b << 10) + (g << 5) + t];
  __syncthreads();
  float sc[8], rf[8], rd[8];
  *(float4*)&sc[0] = *(const float4*)&sjc[(b << 10) + jb * 8];
  *(float4*)&sc[4] = *(const float4*)&sjc[(b << 10) + jb * 8 + 4];
  *(float4*)&rf[0] = *(const float4*)&refj[(b << 10) + jb * 8];
  *(float4*)&rf[4] = *(const float4*)&refj[(b << 10) + jb * 8 + 4];
  *(float4*)&rd[0] = *(const float4*)&rden[(b << 10) + jb * 8];
  *(float4*)&rd[4] = *(const float4*)&rden[(b << 10) + jb * 8 + 4];
  const unsigned char* bp = bm + ((size_t)b << 17) + ((size_t)row0 << 7) + jb;
  _Float16* pp = P16 + ((size_t)b << 20) + ((size_t)row0 << 10) + jb * 8;
#pragma unroll 4
  for (int r = 0; r < 16; ++r) {
    const unsigned m = bp[(size_t)r << 7];
    const float siv = s_si[(half << 4) + r];
    f16x8 ph;
#pragma unroll
    for (int k = 0; k < 8; ++k) {
      float p;
      if (rd[k] < 0.f)
        p = 0.0009765625f;  // 1/1024 uniform (all-masked column)
      else if ((m >> k) & 1)
        p = __expf(lrelu(siv + sc[k]) - rf[k]) * rd[k];
      else
        p = 0.f;
      ph[k] = (_Float16)p;
    }
    *(f16x8*)(pp + ((size_t)r << 10)) = ph;
  }
}

// ---------------------------------------------------------------------------
extern "C" void kernel_launch(void* const* d_in, const int* in_sizes, int n_in,
                              void* d_out, int out_size, void* d_ws,
                              size_t ws_size, hipStream_t stream) {
  const float* X0 = (const float*)d_in[0];
  const int* mask = (const int*)d_in[1];
  const float* W = (const float*)d_in[2];
  const float* Wb = (const float*)d_in[3];
  const float* A = (const float*)d_in[4];
  const float* Ab = (const float*)d_in[5];
  float* out = (float*)d_out;

  const size_t BSD = (size_t)NBATCH * SS * DF;  // 12,582,912 elems
  const size_t BSS = (size_t)NBATCH * SS * SS;  // 16,777,216 elems
  const size_t BS = (size_t)NBATCH * SS;        // 16,384 elems

  char* p = (char*)d_ws;
  _Float16* X16 = (_Float16*)p;   p += BSD * 2;                   // 24 MB
  _Float16* hT16 = (_Float16*)p;  p += BSD * 2;                   // 24 MB
  _Float16* P16 = (_Float16*)p;   p += BSS * 2;                   // 32 MB
  _Float16* W16 = (_Float16*)p;   p += (size_t)2 * DF * DF * 2;   // 2.25 MB
  unsigned char* bmk = (unsigned char*)p; p += BSS / 8;           // 2 MB
  float* psi6 = (float*)p; p += 6 * BS * 4;   // 384 KB
  float* psj6 = (float*)p; p += 6 * BS * 4;   // 384 KB
  float* pden = (float*)p; p += 64 * BS * 4;  // 4 MB
  float* si = (float*)p;   p += BS * 4;
  float* sjc = (float*)p;  p += BS * 4;
  float* refj = (float*)p; p += BS * 4;
  float* rden = (float*)p; p += BS * 4;

  f32tof16_k<<<12288, 256, 0, stream>>>(X0, X16, (int)BSD);
  f32tof16_k<<<1152, 256, 0, stream>>>(W, W16, 2 * DF * DF);
  pack_k<<<8192, 256, 0, stream>>>(mask, bmk);

  for (int l = 0; l < 2; ++l) {
    gemm1_k<<<dim3(128, 6), 256, 0, stream>>>(
        X16, W16 + (size_t)l * DF * DF, Wb + (size_t)l * DF,
        A + (size_t)l * 2 * DF, hT16, psi6, psj6);
    rowfin_k<<<16, 256, 0, stream>>>(psi6, psj6, Ab + l, si, sjc, refj);
    colsum_k<<<dim3(32, 16), 256, 0, stream>>>(bmk, si, sjc, refj, pden);
    colcomb_k<<<64, 256, 0, stream>>>(pden, rden);
    punorm2_k<<<dim3(32, 16), 256, 0, stream>>>(bmk, si, sjc, refj, rden, P16);
    gemm2_k<<<dim3(8, 6, 16), 256, 0, stream>>>(P16, hT16,
                                                out + (size_t)l * BSD, X16,
                                                (l == 0) ? 1 : 0);
  }
}